// Round 5
// baseline (4883.637 us; speedup 1.0000x reference)
//
#include <hip/hip_runtime.h>
#include <math.h>

// Speller round 12: per-batch groups of 8 — narrow every exchange.
//   v11 verdict: attn is exchange-floor-bound at 16.3us/step; compute trims
//   hide inside barrier waits. All exchanges were 32-wide only because the
//   GEMV shared 64 cols across 4 batches. v12: WG <-> (batch b, slice sc):
//   owns 64 u-cols AND 64 score-slots of ONE batch. All three barriers
//   become 8-wide (one batch = one group); the 32 batch-pipelines fully
//   decouple. GEMV streams RT from L2 (coalesced 1KB/inst, ~1.2TB/s/XCD);
//   combine gathers shrink 1536->~530 sc1/WG. Protocol mechanics (sc1
//   publish + cached virgin-line reads + rotating buffers) = v7 verbatim.
//   lstm_coop unchanged (its per-batch variant would push L2 to ~22TB/s).

#define U_   512
#define S_   512
#define T_   128
#define B_   32
#define G4   2048
#define V_   46
#define NWG  256
#define FSTR 32            // flag stride in u32 = 128 B

#define AT_LD(p)     __hip_atomic_load((p), __ATOMIC_RELAXED, __HIP_MEMORY_SCOPE_AGENT)
#define AT_ST(p, v)  __hip_atomic_store((p), (v), __ATOMIC_RELAXED, __HIP_MEMORY_SCOPE_AGENT)

// 1-hop barrier over the 32 WGs of this group (lstm).
__device__ __forceinline__ void group_bar(unsigned* gflags, unsigned seq) {
  __syncthreads();
  const int tid = threadIdx.x;
  if (tid < 32) {
    if (tid == 0)
      AT_ST(&gflags[(blockIdx.x & 31) * FSTR], seq);
    while (!__all(AT_LD(&gflags[tid * FSTR]) >= seq))
      __builtin_amdgcn_s_sleep(1);
  }
  __syncthreads();
}

// 1-hop barrier over the 8 WGs of one batch (attn).
__device__ __forceinline__ void group_bar8(unsigned* gflags, unsigned seq,
                                           int sc) {
  __syncthreads();
  const int tid = threadIdx.x;
  if (tid < 8) {
    if (tid == 0)
      AT_ST(&gflags[sc * FSTR], seq);
    while (!__all(AT_LD(&gflags[tid * FSTR]) >= seq))
      __builtin_amdgcn_s_sleep(1);
  }
  __syncthreads();
}

// ---------------- GEMM: Z[M,2048] = A[M,512] @ W[512,2048] + b ----------------
__global__ __launch_bounds__(256) void gemm_k512(
    const float* __restrict__ A, const float* __restrict__ W,
    const float* __restrict__ b, float* __restrict__ Z) {
  const int tid = threadIdx.x;
  const int j = blockIdx.x * 1024 + tid * 4;
  const int i0 = blockIdx.y * 8;
  float4 bj = *(const float4*)(b + j);
  float4 acc[8];
#pragma unroll
  for (int r = 0; r < 8; ++r) acc[r] = bj;
  const float* Arow = A + (size_t)i0 * U_;
  for (int k = 0; k < U_; ++k) {
    float4 w = *(const float4*)(W + (size_t)k * G4 + j);
#pragma unroll
    for (int r = 0; r < 8; ++r) {
      float a = Arow[(size_t)r * U_ + k];
      acc[r].x = fmaf(a, w.x, acc[r].x);
      acc[r].y = fmaf(a, w.y, acc[r].y);
      acc[r].z = fmaf(a, w.z, acc[r].z);
      acc[r].w = fmaf(a, w.w, acc[r].w);
    }
  }
#pragma unroll
  for (int r = 0; r < 8; ++r)
    *(float4*)(Z + (size_t)(i0 + r) * G4 + j) = acc[r];
}

// ---------------- transpose R[512][2048] -> RT[2048][512] ----------------
__global__ __launch_bounds__(256) void transpose_R(
    const float* __restrict__ R, float* __restrict__ RT) {
  __shared__ float tile[64][65];
  const int c0 = blockIdx.x * 64, k0 = blockIdx.y * 64;
  const int tc = threadIdx.x & 63, tr = threadIdx.x >> 6;
  for (int r = tr; r < 64; r += 4)
    tile[r][tc] = R[(size_t)(k0 + r) * G4 + c0 + tc];
  __syncthreads();
  for (int r = tr; r < 64; r += 4)
    RT[(size_t)(c0 + r) * 512 + k0 + tc] = tile[tc][r];
}

// ---------------- attention LSTM: 32 batch-groups x 8 WGs ------------------
// WG = (batch b, slice sc): 64 u-cols + 64 score-slots of that batch.
// dyn LDS: x_s [512][65] + h_st [512] = 135168 B
// hbuf: rotating [T+1][32][512]; hnbuf: rotating [T][32][512]
__global__ __launch_bounds__(512) void attn_coop(
    const float* __restrict__ x, const float* __restrict__ ZY,
    const float* __restrict__ RT, float* __restrict__ ctxs,
    float* hbuf, float* hnbuf, float* smax, float* ssumg,
    float* ctxpart, unsigned* flags) {
  extern __shared__ float dyn[];
  float* x_s  = dyn;               // [u][65], conflict-free
  float* h_st = dyn + 512 * 65;    // [512]
  __shared__ float zp[256][2];
  __shared__ float p_s[64];
  __shared__ float ctx_s[64];

  const int tid = threadIdx.x;
  const int bid = blockIdx.x;
  const int b   = bid >> 3;                       // batch 0..31
  const int sc  = bid & 7;                        // slice 0..7
  const int u0  = sc * 64;
  // GEMV role mapping: 256 cols (4 gates x 64 u) x 2 k-halves
  const int kh   = tid & 1;
  const int colh = tid >> 1;                      // 0..255
  const int zcol = (colh >> 6) * 512 + u0 + (colh & 63);
  unsigned* gflags = flags + b * 8 * FSTR;

  // x slice: this batch's 64 slots (sc) x 512 u
  for (int idx = tid; idx < 64 * 512; idx += 512) {
    int sl = idx >> 9, u = idx & 511;
    x_s[u * 65 + sl] = x[((size_t)b * S_ + u0 + sl) * U_ + u];
  }
  float c = 0.f, hn_reg = 0.f;
  unsigned seq = 0;
  __syncthreads();

  for (int t = 0; t < T_; ++t) {
    // ---- stage h(t) for this batch (cached: virgin rotating lines) ----
    h_st[tid] = hbuf[(size_t)t * 16384 + b * 512 + tid];
    __syncthreads();
    // ---- GEMV: z-partial from h(LDS) x RT(L2-stream) ----
    {
      const float4* H4 = (const float4*)(h_st + kh * 256);
      const float4* R4 = (const float4*)(RT + (size_t)zcol * 512 + kh * 256);
      float acc = 0.f;
#pragma unroll 8
      for (int i = 0; i < 64; ++i) {
        float4 hv = H4[i];
        float4 rv = R4[i];
        acc = fmaf(hv.x, rv.x, acc); acc = fmaf(hv.y, rv.y, acc);
        acc = fmaf(hv.z, rv.z, acc); acc = fmaf(hv.w, rv.w, acc);
      }
      zp[colh][kh] = acc;
    }
    __syncthreads();
    if (tid < 64) {
      const int u = u0 + tid;
      const float* zy = ZY + ((size_t)b * T_ + t) * G4 + u;
      float zi = zy[0]    + zp[tid][0]       + zp[tid][1];
      float zf = zy[512]  + zp[64 + tid][0]  + zp[64 + tid][1];
      float zg = zy[1024] + zp[128 + tid][0] + zp[128 + tid][1];
      float zo = zy[1536] + zp[192 + tid][0] + zp[192 + tid][1];
      float ig = 1.f / (1.f + expf(-zi));
      float fg = 1.f / (1.f + expf(-zf));
      float gg = tanhf(zg);
      float og = 1.f / (1.f + expf(-zo));
      c = fg * c + ig * gg;
      hn_reg = og * tanhf(c);
      AT_ST(&hnbuf[(size_t)t * 16384 + b * 512 + u], hn_reg);
    }
    group_bar8(gflags, ++seq, sc);                // BAR1: hn(t) complete

    // ---- scores (hn in 8 regs from rotating hnbuf), softmax, partials ----
    {
      const int wv = tid >> 6, ln = tid & 63;
      const float* hnb = hnbuf + (size_t)t * 16384 + b * 512;
      float hreg[8];
#pragma unroll
      for (int k = 0; k < 8; ++k) hreg[k] = hnb[ln + 64 * k];
      for (int si = 0; si < 8; ++si) {
        const int sl = wv * 8 + si;
        float a = 0.f;
#pragma unroll
        for (int k = 0; k < 8; ++k)
          a = fmaf(hreg[k], x_s[(ln + 64 * k) * 65 + sl], a);
#pragma unroll
        for (int off = 32; off; off >>= 1) a += __shfl_down(a, off);
        if (ln == 0) p_s[sl] = a;
      }
    }
    __syncthreads();
    if (tid < 64) {
      float v = p_s[tid];
      float m = v;
#pragma unroll
      for (int off = 32; off; off >>= 1) m = fmaxf(m, __shfl_down(m, off));
      m = __shfl(m, 0);
      float ex = expf(v - m);
      p_s[tid] = ex;
      float sm = ex;
#pragma unroll
      for (int off = 32; off; off >>= 1) sm += __shfl_down(sm, off);
      if (tid == 0) {
        AT_ST(&smax[b * 8 + sc], m);
        AT_ST(&ssumg[b * 8 + sc], sm);
      }
    }
    __syncthreads();
    {
      float a = 0.f;
      const float* xr = x_s + tid * 65;
#pragma unroll 8
      for (int s = 0; s < 64; ++s) a = fmaf(p_s[s], xr[s], a);
      AT_ST(&ctxpart[((size_t)b * 8 + sc) * 512 + tid], a);
    }
    group_bar8(gflags, ++seq, sc);                // BAR2: partials complete

    // ---- combine own u-slice (64 u x 8 j, sc1 gathers) ----
    {
      const int j = tid & 7;
      const int uu = tid >> 3;                    // 0..63
      float lm = AT_LD(&smax[b * 8 + j]);
      float ss = AT_LD(&ssumg[b * 8 + j]);
      float cp = AT_LD(&ctxpart[((size_t)b * 8 + j) * 512 + u0 + uu]);
      float gm = lm;
#pragma unroll
      for (int off = 1; off < 8; off <<= 1)
        gm = fmaxf(gm, __shfl_xor(gm, off));
      float w = expf(lm - gm);
      float st = ss * w, cs = cp * w;
#pragma unroll
      for (int off = 1; off < 8; off <<= 1) {
        st += __shfl_xor(st, off);
        cs += __shfl_xor(cs, off);
      }
      if (j == 0) ctx_s[uu] = cs / st;
    }
    __syncthreads();
    if (tid < 64) {
      const int u = u0 + tid;
      float ctxv = ctx_s[tid];
      c += ctxv;
      float hcar = hn_reg + ctxv;
      AT_ST(&hbuf[(size_t)(t + 1) * 16384 + b * 512 + u], hcar);
      ctxs[((size_t)b * T_ + t) * U_ + u] = ctxv;
    }
    group_bar8(gflags, ++seq, sc);                // BAR3: h(t+1) complete
  }
}

// ---------------- plain LSTM: 8 groups x 32 WGs (v11 verbatim) ------------
// dyn LDS: R_s [64][516] + h_st [4][516] = 140352 B; hbuf rotating
__global__ __launch_bounds__(512) void lstm_coop(
    const float* __restrict__ Zin, const float* __restrict__ R,
    float* __restrict__ seq_out, float* __restrict__ last_out,
    float* hbuf, unsigned* flags) {
  extern __shared__ float dyn[];
  float* R_s  = dyn;                 // [col][516]
  float* h_st = dyn + 64 * 516;      // [b_l][516]
  __shared__ float zp[4][64][2];
  const int tid = threadIdx.x;
  const int bid = blockIdx.x;
  const int g    = bid >> 5;
  const int wgid = bid & 31;
  const int u0   = wgid * 16;
  const int kh  = tid & 1;
  const int b_l = (tid >> 1) & 3;
  const int col = tid >> 3;
  unsigned* gflags = flags + g * 32 * FSTR;

  for (int idx = tid; idx < 64 * 512; idx += 512) {
    int cc = idx & 63, kk = idx >> 6;
    R_s[cc * 516 + kk] = R[(size_t)kk * G4 + (cc >> 4) * 512 + u0 + (cc & 15)];
  }
  float c = 0.f;
  unsigned seq = 0;
  __syncthreads();

  for (int t = 0; t < T_; ++t) {
    {
      const float4* hb4 =
          (const float4*)(hbuf + (size_t)t * 16384 + 4 * g * 512);
      float4 v = hb4[tid];
      *(float4*)(h_st + (tid >> 7) * 516 + (tid & 127) * 4) = v;
    }
    __syncthreads();
    {
      const float4* H4 = (const float4*)(h_st + b_l * 516 + kh * 256);
      const float4* R4 = (const float4*)(R_s + col * 516 + kh * 256);
      float acc = 0.f;
#pragma unroll 8
      for (int i = 0; i < 64; ++i) {
        float4 hv = H4[i];
        float4 rv = R4[i];
        acc = fmaf(hv.x, rv.x, acc); acc = fmaf(hv.y, rv.y, acc);
        acc = fmaf(hv.z, rv.z, acc); acc = fmaf(hv.w, rv.w, acc);
      }
      zp[b_l][col][kh] = acc;
    }
    __syncthreads();
    if (tid < 64) {
      const int bb = tid >> 4, uu = tid & 15;
      const int b = 4 * g + bb, u = u0 + uu;
      const float* zy = Zin + ((size_t)b * T_ + t) * G4 + u;
      float zi = zy[0]    + zp[bb][uu][0]      + zp[bb][uu][1];
      float zf = zy[512]  + zp[bb][16 + uu][0] + zp[bb][16 + uu][1];
      float zg = zy[1024] + zp[bb][32 + uu][0] + zp[bb][32 + uu][1];
      float zo = zy[1536] + zp[bb][48 + uu][0] + zp[bb][48 + uu][1];
      float ig = 1.f / (1.f + expf(-zi));
      float fg = 1.f / (1.f + expf(-zf));
      float gg = tanhf(zg);
      float og = 1.f / (1.f + expf(-zo));
      c = fg * c + ig * gg;
      float hv2 = og * tanhf(c);
      AT_ST(&hbuf[(size_t)(t + 1) * 16384 + b * 512 + u], hv2);
      if (seq_out) seq_out[((size_t)b * T_ + t) * U_ + u] = hv2;
      if (last_out && t == T_ - 1) last_out[b * U_ + u] = hv2;
    }
    group_bar(gflags, ++seq);
  }
}

// ---------------- decoder ----------------
__global__ __launch_bounds__(64) void final_k(
    const float* __restrict__ hT, const float* __restrict__ Wd,
    const float* __restrict__ bd, float* __restrict__ out) {
  const int b = blockIdx.x;
  const int v = threadIdx.x;
  float acc = (v < V_) ? bd[v] : -INFINITY;
  if (v < V_) {
    for (int k = 0; k < U_; ++k)
      acc = fmaf(hT[(size_t)b * U_ + k], Wd[(size_t)k * V_ + v], acc);
  }
  float m = acc;
#pragma unroll
  for (int off = 32; off; off >>= 1) m = fmaxf(m, __shfl_down(m, off));
  m = __shfl(m, 0);
  float e = (v < V_) ? expf(acc - m) : 0.f;
  float s = e;
#pragma unroll
  for (int off = 32; off; off >>= 1) s += __shfl_down(s, off);
  s = __shfl(s, 0);
  if (v < V_) out[(size_t)b * V_ + v] = e / s;
}

extern "C" void kernel_launch(void* const* d_in, const int* in_sizes, int n_in,
                              void* d_out, int out_size, void* d_ws, size_t ws_size,
                              hipStream_t stream) {
  const float* x   = (const float*)d_in[0];
  const float* y   = (const float*)d_in[1];
  const float* W_a = (const float*)d_in[2];
  const float* R_a = (const float*)d_in[3];
  const float* b_a = (const float*)d_in[4];
  const float* W1  = (const float*)d_in[5];
  const float* R1  = (const float*)d_in[6];
  const float* b1  = (const float*)d_in[7];
  const float* W2  = (const float*)d_in[8];
  const float* R2  = (const float*)d_in[9];
  const float* b2  = (const float*)d_in[10];
  const float* Wd  = (const float*)d_in[11];
  const float* bd  = (const float*)d_in[12];
  float* out = (float*)d_out;

  float* ZBUF  = (float*)d_ws;                   // 8388608 f
  float* SEQ   = ZBUF + (size_t)8388608;         // 2097152 f
  float* RT    = SEQ + (size_t)2097152;          // 1048576 f
  float* HROT  = RT + (size_t)1048576;           // 129*16384 = 2113536 f
  float* HNROT = HROT + (size_t)2113536;         // 128*16384 = 2097152 f
  float* SMAX  = HNROT + (size_t)2097152;        // 256
  float* SSUM  = SMAX + 256;                     // 256
  float* CTXP  = SSUM + 256;                     // 131072
  float* HT    = CTXP + 131072;                  // 16384
  unsigned* BAR = (unsigned*)(HT + 16384);

  // flag regions: attn 32 groups x 8 slots; lstm 8 groups x 32 slots
  const int REGION = 8192;                       // u32 each
  unsigned* FLG_A = BAR;
  unsigned* FLG_1 = BAR + REGION;
  unsigned* FLG_2 = BAR + 2 * REGION;

  const int attn_lds = (512 * 65 + 512) * 4;        // 135168 B
  const int lstm_lds = (64 * 516 + 4 * 516) * 4;    // 140352 B
  hipFuncSetAttribute((const void*)attn_coop,
                      hipFuncAttributeMaxDynamicSharedMemorySize, attn_lds);
  hipFuncSetAttribute((const void*)lstm_coop,
                      hipFuncAttributeMaxDynamicSharedMemorySize, lstm_lds);

  dim3 ggrid(2, 512);
  hipMemsetAsync(BAR, 0, 3 * REGION * 4, stream);

  gemm_k512<<<ggrid, 256, 0, stream>>>(y, W_a, b_a, ZBUF);
  transpose_R<<<dim3(32, 8), 256, 0, stream>>>(R_a, RT);
  hipMemsetAsync(HROT, 0, 16384 * 4, stream);          // h[0] = 0
  attn_coop<<<NWG, 512, attn_lds, stream>>>(x, ZBUF, RT, SEQ, HROT, HNROT,
                                            SMAX, SSUM, CTXP, FLG_A);
  gemm_k512<<<ggrid, 256, 0, stream>>>(SEQ, W1, b1, ZBUF);
  hipMemsetAsync(HROT, 0, 16384 * 4, stream);          // h1[0] = 0
  lstm_coop<<<NWG, 512, lstm_lds, stream>>>(ZBUF, R1, SEQ, nullptr, HROT,
                                            FLG_1);
  gemm_k512<<<ggrid, 256, 0, stream>>>(SEQ, W2, b2, ZBUF);
  hipMemsetAsync(HROT, 0, 16384 * 4, stream);          // h2[0] = 0
  lstm_coop<<<NWG, 512, lstm_lds, stream>>>(ZBUF, R2, nullptr, HT, HROT,
                                            FLG_2);
  final_k<<<B_, 64, 0, stream>>>(HT, Wd, bd, out);
}

// Round 6
// 3982.889 us; speedup vs baseline: 1.2262x; 1.2262x over previous
//
#include <hip/hip_runtime.h>
#include <math.h>

// Speller round 13: v11 restored (verified best, ~3990us) + dispatch-overhead
//   shaves. Ledger: v8 redundancy ✗, v9 occupancy ✗, v10 fusion ✗,
//   v11 compute-trim flat, v12 narrow-groups ✗ (L2 GEMV: 512KB/WG/step @
//   ~135GB/s/CU = +3us/step). v7/v11 structure = local optimum; runtime is
//   sync-latency-bound: 128 steps x (3 attn + 2 lstm exchanges) x ~4us IF$
//   RTT. v13 removes inter-kernel overhead only:
//   - h(0)=0 folded into attn/lstm staging (t==0 branch) -> 3 memsets gone
//   - decoder folded bit-identically into lstm2 epilogue -> final_k gone

#define U_   512
#define S_   512
#define T_   128
#define B_   32
#define G4   2048
#define V_   46
#define NWG  256
#define FSTR 32            // flag stride in u32 = 128 B

#define AT_LD(p)     __hip_atomic_load((p), __ATOMIC_RELAXED, __HIP_MEMORY_SCOPE_AGENT)
#define AT_ST(p, v)  __hip_atomic_store((p), (v), __ATOMIC_RELAXED, __HIP_MEMORY_SCOPE_AGENT)

// 1-hop barrier over the 32 WGs of this group. gflags = 32 padded slots.
__device__ __forceinline__ void group_bar(unsigned* gflags, unsigned seq) {
  __syncthreads();   // all waves' stores drained (vmcnt) before arrival
  const int tid = threadIdx.x;
  if (tid < 32) {
    if (tid == 0)
      AT_ST(&gflags[(blockIdx.x & 31) * FSTR], seq);
    while (!__all(AT_LD(&gflags[tid * FSTR]) >= seq))
      __builtin_amdgcn_s_sleep(1);
  }
  __syncthreads();
}

// ---------------- GEMM: Z[M,2048] = A[M,512] @ W[512,2048] + b ----------------
__global__ __launch_bounds__(256) void gemm_k512(
    const float* __restrict__ A, const float* __restrict__ W,
    const float* __restrict__ b, float* __restrict__ Z) {
  const int tid = threadIdx.x;
  const int j = blockIdx.x * 1024 + tid * 4;
  const int i0 = blockIdx.y * 8;
  float4 bj = *(const float4*)(b + j);
  float4 acc[8];
#pragma unroll
  for (int r = 0; r < 8; ++r) acc[r] = bj;
  const float* Arow = A + (size_t)i0 * U_;
  for (int k = 0; k < U_; ++k) {
    float4 w = *(const float4*)(W + (size_t)k * G4 + j);
#pragma unroll
    for (int r = 0; r < 8; ++r) {
      float a = Arow[(size_t)r * U_ + k];
      acc[r].x = fmaf(a, w.x, acc[r].x);
      acc[r].y = fmaf(a, w.y, acc[r].y);
      acc[r].z = fmaf(a, w.z, acc[r].z);
      acc[r].w = fmaf(a, w.w, acc[r].w);
    }
  }
#pragma unroll
  for (int r = 0; r < 8; ++r)
    *(float4*)(Z + (size_t)(i0 + r) * G4 + j) = acc[r];
}

// ---------------- transpose R[512][2048] -> RT[2048][512] ----------------
__global__ __launch_bounds__(256) void transpose_R(
    const float* __restrict__ R, float* __restrict__ RT) {
  __shared__ float tile[64][65];
  const int c0 = blockIdx.x * 64, k0 = blockIdx.y * 64;
  const int tc = threadIdx.x & 63, tr = threadIdx.x >> 6;
  for (int r = tr; r < 64; r += 4)
    tile[r][tc] = R[(size_t)(k0 + r) * G4 + c0 + tc];
  __syncthreads();
  for (int r = tr; r < 64; r += 4)
    RT[(size_t)(c0 + r) * 512 + k0 + tc] = tile[tc][r];
}

// ---------------- attention LSTM: 8 groups x 32 WGs, 4 batches/group ------
// dyn LDS: x_s [512][65] + h_st [4][516]  = 141376 B
// hbuf: rotating [T+1][32][512] (slot 0 unused: t==0 zero-fills in-kernel)
// hnbuf: rotating [T][32][512]
__global__ __launch_bounds__(512) void attn_coop(
    const float* __restrict__ x, const float* __restrict__ ZY,
    const float* __restrict__ RT, float* __restrict__ ctxs,
    float* hbuf, float* hnbuf, float* smax, float* ssumg,
    float* ctxpart, unsigned* flags) {
  extern __shared__ float dyn[];
  float* x_s  = dyn;                 // [u][65], conflict-free
  float* h_st = dyn + 512 * 65;      // [b_l][516]
  __shared__ float zp[4][64][2];
  __shared__ float p_s[64];
  __shared__ float ctx_s[64];

  const int tid = threadIdx.x;
  const int bid = blockIdx.x;
  const int g    = bid >> 5;
  const int wgid = bid & 31;
  const int u0   = wgid * 16;
  // GEMV role mapping: 64 cols x 4 batches x 2 k-halves
  const int kh  = tid & 1;
  const int b_l = (tid >> 1) & 3;
  const int col = tid >> 3;                       // 0..63
  const int zcol = (col >> 4) * 512 + u0 + (col & 15);
  // attention role mapping
  const int b_att = 4 * g + (wgid >> 3);
  const int sc = wgid & 7;
  unsigned* gflags = flags + g * 32 * FSTR;

  for (int idx = tid; idx < 64 * 512; idx += 512) {
    int sl = idx >> 9, u = idx & 511;
    x_s[u * 65 + sl] = x[((size_t)b_att * S_ + sc * 64 + sl) * U_ + u];
  }
  float c = 0.f, hn_reg = 0.f;
  unsigned seq = 0;
  __syncthreads();

  for (int t = 0; t < T_; ++t) {
    // ---- stage h slot t (cached float4 burst: virgin lines -> IF$) ----
    {
      float4 v = make_float4(0.f, 0.f, 0.f, 0.f);
      if (t) {
        const float4* hb4 =
            (const float4*)(hbuf + (size_t)t * 16384 + 4 * g * 512);
        v = hb4[tid];
      }
      *(float4*)(h_st + (tid >> 7) * 516 + (tid & 127) * 4) = v;
    }
    __syncthreads();
    // ---- GEMV: z-partial from h(LDS) x RT(L2) ----
    {
      const float4* H4 = (const float4*)(h_st + b_l * 516 + kh * 256);
      const float4* R4 = (const float4*)(RT + (size_t)zcol * 512 + kh * 256);
      float acc = 0.f;
#pragma unroll 8
      for (int i = 0; i < 64; ++i) {
        float4 hv = H4[i];
        float4 rv = R4[i];
        acc = fmaf(hv.x, rv.x, acc); acc = fmaf(hv.y, rv.y, acc);
        acc = fmaf(hv.z, rv.z, acc); acc = fmaf(hv.w, rv.w, acc);
      }
      zp[b_l][col][kh] = acc;
    }
    __syncthreads();
    if (tid < 64) {
      const int bb = tid >> 4, uu = tid & 15;
      const int b = 4 * g + bb, u = u0 + uu;
      const float* zy = ZY + ((size_t)b * T_ + t) * G4 + u;
      float zi = zy[0]    + zp[bb][uu][0]      + zp[bb][uu][1];
      float zf = zy[512]  + zp[bb][16 + uu][0] + zp[bb][16 + uu][1];
      float zg = zy[1024] + zp[bb][32 + uu][0] + zp[bb][32 + uu][1];
      float zo = zy[1536] + zp[bb][48 + uu][0] + zp[bb][48 + uu][1];
      float ig = 1.f / (1.f + expf(-zi));
      float fg = 1.f / (1.f + expf(-zf));
      float gg = tanhf(zg);
      float og = 1.f / (1.f + expf(-zo));
      c = fg * c + ig * gg;
      hn_reg = og * tanhf(c);
      AT_ST(&hnbuf[(size_t)t * 16384 + b * 512 + u], hn_reg);
    }
    group_bar(gflags, ++seq);

    // ---- scores (hn in 8 regs, read once from rotating hnbuf slot),
    //      local softmax, ctx partials ----
    {
      const int wv = tid >> 6, ln = tid & 63;
      const float* hnb = hnbuf + (size_t)t * 16384 + b_att * 512;
      float hreg[8];
#pragma unroll
      for (int k = 0; k < 8; ++k) hreg[k] = hnb[ln + 64 * k];
      for (int si = 0; si < 8; ++si) {
        const int sl = wv * 8 + si;
        float a = 0.f;
#pragma unroll
        for (int k = 0; k < 8; ++k)
          a = fmaf(hreg[k], x_s[(ln + 64 * k) * 65 + sl], a);
#pragma unroll
        for (int off = 32; off; off >>= 1) a += __shfl_down(a, off);
        if (ln == 0) p_s[sl] = a;
      }
    }
    __syncthreads();
    if (tid < 64) {
      float v = p_s[tid];
      float m = v;
#pragma unroll
      for (int off = 32; off; off >>= 1) m = fmaxf(m, __shfl_down(m, off));
      m = __shfl(m, 0);
      float ex = expf(v - m);
      p_s[tid] = ex;
      float sm = ex;
#pragma unroll
      for (int off = 32; off; off >>= 1) sm += __shfl_down(sm, off);
      if (tid == 0) {
        AT_ST(&smax[b_att * 8 + sc], m);
        AT_ST(&ssumg[b_att * 8 + sc], sm);
      }
    }
    __syncthreads();
    {
      float a = 0.f;
      const float* xr = x_s + tid * 65;
#pragma unroll 8
      for (int s = 0; s < 64; ++s) a = fmaf(p_s[s], xr[s], a);
      AT_ST(&ctxpart[((size_t)b_att * 8 + sc) * 512 + tid], a);
    }
    group_bar(gflags, ++seq);

    // ---- combine slices (parallel over 512 thr: pair x j, sc1 gathers) ----
    {
      const int j = tid & 7;
      const int pair = tid >> 3;            // 0..63 == gates-thread index
      const int bb = pair >> 4, uu = pair & 15;
      const int b = 4 * g + bb, u = u0 + uu;
      float lm = AT_LD(&smax[b * 8 + j]);
      float ss = AT_LD(&ssumg[b * 8 + j]);
      float cp = AT_LD(&ctxpart[((size_t)b * 8 + j) * 512 + u]);
      float gm = lm;
#pragma unroll
      for (int off = 1; off < 8; off <<= 1)
        gm = fmaxf(gm, __shfl_xor(gm, off));
      float w = expf(lm - gm);
      float st = ss * w, cs = cp * w;
#pragma unroll
      for (int off = 1; off < 8; off <<= 1) {
        st += __shfl_xor(st, off);
        cs += __shfl_xor(cs, off);
      }
      if (j == 0) ctx_s[pair] = cs / st;
    }
    __syncthreads();
    if (tid < 64) {
      const int bb = tid >> 4, uu = tid & 15;
      const int b = 4 * g + bb, u = u0 + uu;
      float ctxv = ctx_s[tid];
      c += ctxv;
      float hcar = hn_reg + ctxv;
      AT_ST(&hbuf[(size_t)(t + 1) * 16384 + b * 512 + u], hcar);
      ctxs[((size_t)b * T_ + t) * U_ + u] = ctxv;
    }
    group_bar(gflags, ++seq);
  }
}

// ---------------- plain LSTM: 8 groups x 32 WGs ----------------
// dyn LDS: R_s [64][516] + h_st [4][516] = 140352 B; hbuf rotating
// (slot 0 unused: t==0 zero-fills in-kernel)
// If Wd != nullptr: decoder folded into epilogue (bit-identical to final_k).
__global__ __launch_bounds__(512) void lstm_coop(
    const float* __restrict__ Zin, const float* __restrict__ R,
    float* __restrict__ seq_out, float* hbuf, unsigned* flags,
    const float* __restrict__ Wd, const float* __restrict__ bd,
    float* __restrict__ out) {
  extern __shared__ float dyn[];
  float* R_s  = dyn;                 // [col][516]
  float* h_st = dyn + 64 * 516;      // [b_l][516]
  __shared__ float zp[4][64][2];
  const int tid = threadIdx.x;
  const int bid = blockIdx.x;
  const int g    = bid >> 5;
  const int wgid = bid & 31;
  const int u0   = wgid * 16;
  const int kh  = tid & 1;
  const int b_l = (tid >> 1) & 3;
  const int col = tid >> 3;
  unsigned* gflags = flags + g * 32 * FSTR;

  // one-time R slice -> LDS (transposed to [col][k])
  for (int idx = tid; idx < 64 * 512; idx += 512) {
    int cc = idx & 63, kk = idx >> 6;
    R_s[cc * 516 + kk] = R[(size_t)kk * G4 + (cc >> 4) * 512 + u0 + (cc & 15)];
  }
  float c = 0.f;
  unsigned seq = 0;
  __syncthreads();

  for (int t = 0; t < T_; ++t) {
    {
      float4 v = make_float4(0.f, 0.f, 0.f, 0.f);
      if (t) {
        const float4* hb4 =
            (const float4*)(hbuf + (size_t)t * 16384 + 4 * g * 512);
        v = hb4[tid];
      }
      *(float4*)(h_st + (tid >> 7) * 516 + (tid & 127) * 4) = v;
    }
    __syncthreads();
    {
      const float4* H4 = (const float4*)(h_st + b_l * 516 + kh * 256);
      const float4* R4 = (const float4*)(R_s + col * 516 + kh * 256);
      float acc = 0.f;
#pragma unroll 8
      for (int i = 0; i < 64; ++i) {
        float4 hv = H4[i];
        float4 rv = R4[i];
        acc = fmaf(hv.x, rv.x, acc); acc = fmaf(hv.y, rv.y, acc);
        acc = fmaf(hv.z, rv.z, acc); acc = fmaf(hv.w, rv.w, acc);
      }
      zp[b_l][col][kh] = acc;
    }
    __syncthreads();
    if (tid < 64) {
      const int bb = tid >> 4, uu = tid & 15;
      const int b = 4 * g + bb, u = u0 + uu;
      const float* zy = Zin + ((size_t)b * T_ + t) * G4 + u;
      float zi = zy[0]    + zp[bb][uu][0]      + zp[bb][uu][1];
      float zf = zy[512]  + zp[bb][16 + uu][0] + zp[bb][16 + uu][1];
      float zg = zy[1024] + zp[bb][32 + uu][0] + zp[bb][32 + uu][1];
      float zo = zy[1536] + zp[bb][48 + uu][0] + zp[bb][48 + uu][1];
      float ig = 1.f / (1.f + expf(-zi));
      float fg = 1.f / (1.f + expf(-zf));
      float gg = tanhf(zg);
      float og = 1.f / (1.f + expf(-zo));
      c = fg * c + ig * gg;
      float hv2 = og * tanhf(c);
      AT_ST(&hbuf[(size_t)(t + 1) * 16384 + b * 512 + u], hv2);
      if (seq_out) seq_out[((size_t)b * T_ + t) * U_ + u] = hv2;
    }
    group_bar(gflags, ++seq);
  }

  // ---- folded decoder (lstm2 only): one wave per batch, wgid 0 of each
  //      group; bit-identical accumulation/reduction order to final_k ----
  if (Wd && wgid == 0 && tid < 256) {
    const int b = 4 * g + (tid >> 6);
    const int v = tid & 63;
    const float* hT = hbuf + (size_t)T_ * 16384 + (size_t)b * 512;
    float acc = (v < V_) ? bd[v] : -INFINITY;
    if (v < V_) {
      for (int k = 0; k < U_; ++k)
        acc = fmaf(hT[k], Wd[(size_t)k * V_ + v], acc);
    }
    float m = acc;
#pragma unroll
    for (int off = 32; off; off >>= 1) m = fmaxf(m, __shfl_down(m, off));
    m = __shfl(m, 0);
    float e = (v < V_) ? expf(acc - m) : 0.f;
    float s = e;
#pragma unroll
    for (int off = 32; off; off >>= 1) s += __shfl_down(s, off);
    s = __shfl(s, 0);
    if (v < V_) out[(size_t)b * V_ + v] = e / s;
  }
}

extern "C" void kernel_launch(void* const* d_in, const int* in_sizes, int n_in,
                              void* d_out, int out_size, void* d_ws, size_t ws_size,
                              hipStream_t stream) {
  const float* x   = (const float*)d_in[0];
  const float* y   = (const float*)d_in[1];
  const float* W_a = (const float*)d_in[2];
  const float* R_a = (const float*)d_in[3];
  const float* b_a = (const float*)d_in[4];
  const float* W1  = (const float*)d_in[5];
  const float* R1  = (const float*)d_in[6];
  const float* b1  = (const float*)d_in[7];
  const float* W2  = (const float*)d_in[8];
  const float* R2  = (const float*)d_in[9];
  const float* b2  = (const float*)d_in[10];
  const float* Wd  = (const float*)d_in[11];
  const float* bd  = (const float*)d_in[12];
  float* out = (float*)d_out;

  float* ZBUF  = (float*)d_ws;                   // 8388608 f
  float* SEQ   = ZBUF + (size_t)8388608;         // 2097152 f
  float* RT    = SEQ + (size_t)2097152;          // 1048576 f
  float* HROT  = RT + (size_t)1048576;           // 129*16384 = 2113536 f
  float* HNROT = HROT + (size_t)2113536;         // 128*16384 = 2097152 f
  float* SMAX  = HNROT + (size_t)2097152;        // 256
  float* SSUM  = SMAX + 256;                     // 256
  float* CTXP  = SSUM + 256;                     // 131072
  float* HT    = CTXP + 131072;                  // 16384 (unused, kept for layout)
  unsigned* BAR = (unsigned*)(HT + 16384);

  // per kernel-instance: 8 groups x 32 flags x FSTR
  const int REGION = 8 * 32 * FSTR;              // 8192 u32
  unsigned* FLG_A = BAR;
  unsigned* FLG_1 = BAR + REGION;
  unsigned* FLG_2 = BAR + 2 * REGION;

  const int attn_lds = (512 * 65 + 4 * 516) * 4;    // 141376 B
  const int lstm_lds = (64 * 516 + 4 * 516) * 4;    // 140352 B
  hipFuncSetAttribute((const void*)attn_coop,
                      hipFuncAttributeMaxDynamicSharedMemorySize, attn_lds);
  hipFuncSetAttribute((const void*)lstm_coop,
                      hipFuncAttributeMaxDynamicSharedMemorySize, lstm_lds);

  dim3 ggrid(2, 512);
  hipMemsetAsync(BAR, 0, 3 * REGION * 4, stream);

  gemm_k512<<<ggrid, 256, 0, stream>>>(y, W_a, b_a, ZBUF);
  transpose_R<<<dim3(32, 8), 256, 0, stream>>>(R_a, RT);
  attn_coop<<<NWG, 512, attn_lds, stream>>>(x, ZBUF, RT, SEQ, HROT, HNROT,
                                            SMAX, SSUM, CTXP, FLG_A);
  gemm_k512<<<ggrid, 256, 0, stream>>>(SEQ, W1, b1, ZBUF);
  lstm_coop<<<NWG, 512, lstm_lds, stream>>>(ZBUF, R1, SEQ, HROT, FLG_1,
                                            nullptr, nullptr, nullptr);
  gemm_k512<<<ggrid, 256, 0, stream>>>(SEQ, W2, b2, ZBUF);
  lstm_coop<<<NWG, 512, lstm_lds, stream>>>(ZBUF, R2, nullptr, HROT, FLG_2,
                                            Wd, bd, out);
}